// Round 7
// baseline (184.074 us; speedup 1.0000x reference)
//
#include <hip/hip_runtime.h>
#include <math.h>

#define TSTEPS 200
#define NROTS  40      // 5*NQ*NL params per timestep circuit (2 layers)
#define BLK    256
#define DEG    3

// Packed pair of adjacent amplitudes: R[j] = (re[2j], re[2j+1]), I[j] likewise.
// Gates with target-bit >= 2 act identically on both halves -> v_pk_fma_f32.
typedef float f2v __attribute__((ext_vector_type(2)));

__device__ __forceinline__ f2v vs(float x) { return (f2v){x, x}; }

__device__ __forceinline__ void fsc(float h, float& s, float& c) {
    s = __sinf(h); c = __cosf(h);
}

// Fused U = RZ(h3)*RY(h2)*RX(h1); only u00,u01 needed. Verified rounds 2-6.
__device__ __forceinline__ void make_u(float h1, float h2, float h3, float* u) {
    float s1, c1, s2, c2, s3, c3;
    fsc(h1, s1, c1); fsc(h2, s2, c2); fsc(h3, s3, c3);
    float A = c1 * c2, Bv = s1 * s2, C = c1 * s2, D = s1 * c2;
    u[0] =  c3 * A + s3 * Bv;      // u00r
    u[1] =  c3 * Bv - s3 * A;      // u00i
    u[2] = -(c3 * C + s3 * D);     // u01r
    u[3] =  s3 * C - c3 * D;       // u01i
}

// ---- packed gates (state bit >= 2 -> packed-pair bit PB = BIT/2) ----
template<int PB>
__device__ __forceinline__ void g_u2_pk(f2v* R, f2v* I, const float* u) {
    const f2v u00r = vs(u[0]), u00i = vs(u[1]), u01r = vs(u[2]), u01i = vs(u[3]);
    #pragma unroll
    for (int pj = 0; pj < 8; ++pj) {
        if (pj & PB) continue;
        const int qj = pj | PB;
        f2v a0r = R[pj], a0i = I[pj], a1r = R[qj], a1i = I[qj];
        R[pj] =  u00r*a0r - u00i*a0i + u01r*a1r - u01i*a1i;
        I[pj] =  u00r*a0i + u00i*a0r + u01r*a1i + u01i*a1r;
        R[qj] = -(u01r*a0r) - u01i*a0i + u00r*a1r + u00i*a1i;
        I[qj] = -(u01r*a0i) + u01i*a0r + u00r*a1i - u00i*a1r;
    }
}

// g_u2 on wire 3 (BIT=1): pairs live inside one register -> scalar halves.
__device__ __forceinline__ void g_u2_b1(f2v* R, f2v* I, const float* u) {
    const float u00r = u[0], u00i = u[1], u01r = u[2], u01i = u[3];
    #pragma unroll
    for (int j = 0; j < 8; ++j) {
        float a0r = R[j].x, a0i = I[j].x, a1r = R[j].y, a1i = I[j].y;
        R[j].x =  u00r*a0r - u00i*a0i + u01r*a1r - u01i*a1i;
        I[j].x =  u00r*a0i + u00i*a0r + u01r*a1i + u01i*a1r;
        R[j].y = -u01r*a0r - u01i*a0i + u00r*a1r + u00i*a1i;
        I[j].y = -u01r*a0i + u01i*a0r + u00r*a1i - u00i*a1r;
    }
}

// CRX, control and target bits both >= 2: fully packed. PC=CBIT/2, PT=TBIT/2.
template<int PC, int PT>
__device__ __forceinline__ void g_crx_pk(f2v* R, f2v* I, float s, float c) {
    const f2v sv = vs(s), cv = vs(c);
    #pragma unroll
    for (int pj = 0; pj < 8; ++pj) {
        if (!(pj & PC) || (pj & PT)) continue;
        const int qj = pj | PT;
        f2v a0r = R[pj], a0i = I[pj], a1r = R[qj], a1i = I[qj];
        R[pj] = cv*a0r + sv*a1i;
        I[pj] = cv*a0i - sv*a1r;
        R[qj] = cv*a1r + sv*a0i;
        I[qj] = cv*a1i - sv*a0r;
    }
}

// CRX with target bit 1 (x<->y inside a register), control bit>=2: j & JC, JC=CBIT/2.
template<int JC>
__device__ __forceinline__ void g_crx_t1(f2v* R, f2v* I, float s, float c) {
    #pragma unroll
    for (int j = 0; j < 8; ++j) {
        if (!(j & JC)) continue;
        float a0r = R[j].x, a0i = I[j].x, a1r = R[j].y, a1i = I[j].y;
        R[j].x = c*a0r + s*a1i;
        I[j].x = c*a0i - s*a1r;
        R[j].y = c*a1r + s*a0i;
        I[j].y = c*a1i - s*a0r;
    }
}

// CRX with control bit 1 (only .y halves active), target bit>=2: PT=TBIT/2.
template<int PT>
__device__ __forceinline__ void g_crx_c1(f2v* R, f2v* I, float s, float c) {
    #pragma unroll
    for (int j = 0; j < 8; ++j) {
        if (j & PT) continue;
        const int qj = j | PT;
        float a0r = R[j].y, a0i = I[j].y, a1r = R[qj].y, a1i = I[qj].y;
        R[j].y  = c*a0r + s*a1i;
        I[j].y  = c*a0i - s*a1r;
        R[qj].y = c*a1r + s*a0i;
        I[qj].y = c*a1i - s*a0r;
    }
}

// Gate order identical to verified rounds 2-6; packing variants per wire pair:
// wires: 0->BIT8, 1->BIT4, 2->BIT2, 3->BIT1.
__device__ __forceinline__ void apply_layer_pk(f2v* R, f2v* I,
                                               const float (&u)[4][4],
                                               const float (&cs)[8][2]) {
    g_u2_pk<4>(R, I, u[0]);                      // wire 0 (BIT 8)
    g_u2_pk<2>(R, I, u[1]);                      // wire 1 (BIT 4)
    g_u2_pk<1>(R, I, u[2]);                      // wire 2 (BIT 2)
    g_u2_b1  (R, I, u[3]);                       // wire 3 (BIT 1)
    g_crx_pk<4, 2>(R, I, cs[0][0], cs[0][1]);    // crx C8,T4
    g_crx_pk<2, 1>(R, I, cs[1][0], cs[1][1]);    // crx C4,T2
    g_crx_t1<1>   (R, I, cs[2][0], cs[2][1]);    // crx C2,T1
    g_crx_c1<4>   (R, I, cs[3][0], cs[3][1]);    // crx C1,T8
    g_crx_c1<1>   (R, I, cs[4][0], cs[4][1]);    // crx C1,T2
    g_crx_pk<1, 2>(R, I, cs[5][0], cs[5][1]);    // crx C2,T4
    g_crx_pk<2, 4>(R, I, cs[6][0], cs[6][1]);    // crx C4,T8
    g_crx_t1<4>   (R, I, cs[7][0], cs[7][1]);    // crx C8,T1
}

// Reduce-scatter halving step over 16 packed values; template-constant indices
// (round-3-verified pattern).
template<int S, int HALF>
__device__ __forceinline__ void rstep_pk(f2v* W, int lane) {
    const bool hi = (lane >> S) & 1;
    #pragma unroll
    for (int j = 0; j < HALF; ++j) {
        f2v send = hi ? W[j] : W[j + HALF];
        f2v keep = hi ? W[j + HALF] : W[j];
        f2v got;
        got.x = __shfl_xor(send.x, 1 << S, 64);
        got.y = __shfl_xor(send.y, 1 << S, 64);
        W[j] = keep + got;
    }
}

// One block per batch element. Thread t simulates timestep t (t>=200: coeff 0).
extern "C" __global__ void __launch_bounds__(BLK)
qac_kernel(const float* __restrict__ tp,    // (B, T, NROTS)
           const float* __restrict__ poly,  // (DEG+1,)
           const float* __restrict__ mixr,  // (T,)
           const float* __restrict__ mixi,  // (T,)
           const float* __restrict__ qff,   // (20,)
           float* __restrict__ out)         // (B, 12)
{
    // Float layout of s_wP/s_accP is identical to rounds 5/6 planar arrays:
    // floats [0..15] = re amps, [16..31] = im amps.
    __shared__ f2v s_redP[4][16];
    __shared__ f2v s_wP[16];
    __shared__ f2v s_accP[16];

    const int b    = blockIdx.x;
    const int tid  = threadIdx.x;
    const int lane = tid & 63;
    const int wv   = tid >> 6;

    if (tid < 16) {
        s_wP[tid]   = (f2v){tid == 0 ? 1.f : 0.f, 0.f};
        s_accP[tid] = (f2v){tid == 0 ? poly[0] : 0.f, 0.f};
    }

    float cr_ = 0.f, ci_ = 0.f;
    if (tid < TSTEPS) { cr_ = mixr[tid]; ci_ = mixi[tid]; }
    const int mt = (tid < TSTEPS) ? tid : (TSTEPS - 1);
    const float4* p4 = (const float4*)(tp + (size_t)b * (TSTEPS * NROTS) + mt * NROTS);

    // ---- hoist ALL trig out of the QSVT loop (params identical each pass) ----
    float tu[2][4][4];   // [layer][wire][u00r,u00i,u01r,u01i]
    float tc[2][8][2];   // [layer][crx gate][s,c]
    #pragma unroll
    for (int L = 0; L < 2; ++L) {
        float4 f0 = p4[5*L+0], f1 = p4[5*L+1], f2q = p4[5*L+2], f3 = p4[5*L+3], f4 = p4[5*L+4];
        make_u(0.5f*f0.x,  0.5f*f0.y,  0.5f*f0.z,  tu[L][0]);
        make_u(0.5f*f0.w,  0.5f*f1.x,  0.5f*f1.y,  tu[L][1]);
        make_u(0.5f*f1.z,  0.5f*f1.w,  0.5f*f2q.x, tu[L][2]);
        make_u(0.5f*f2q.y, 0.5f*f2q.z, 0.5f*f2q.w, tu[L][3]);
        fsc(0.5f*f3.x, tc[L][0][0], tc[L][0][1]);
        fsc(0.5f*f3.y, tc[L][1][0], tc[L][1][1]);
        fsc(0.5f*f3.z, tc[L][2][0], tc[L][2][1]);
        fsc(0.5f*f3.w, tc[L][3][0], tc[L][3][1]);
        fsc(0.5f*f4.x, tc[L][4][0], tc[L][4][1]);
        fsc(0.5f*f4.y, tc[L][5][0], tc[L][5][1]);
        fsc(0.5f*f4.z, tc[L][6][0], tc[L][6][1]);
        fsc(0.5f*f4.w, tc[L][7][0], tc[L][7][1]);
    }

    // reduce-scatter destination: packed-value index = bitrev4(lane&15) (verified r3)
    const int vidx = ((lane & 1) << 3) | ((lane & 2) << 1) | ((lane & 4) >> 1) | ((lane & 8) >> 3);

    __syncthreads();

    #pragma unroll 1
    for (int k = 1; k <= DEG; ++k) {
        f2v W[16];                 // W[0..7] = re pairs, W[8..15] = im pairs
        #pragma unroll
        for (int j = 0; j < 16; ++j) W[j] = s_wP[j];

        apply_layer_pk(W, W + 8, tu[0], tc[0]);
        apply_layer_pk(W, W + 8, tu[1], tc[1]);

        // scale by this timestep's LCU coefficient (0 for lanes t>=200)
        #pragma unroll
        for (int j = 0; j < 8; ++j) {
            f2v r = W[j], im = W[8 + j];
            W[j]     = vs(cr_)*r - vs(ci_)*im;
            W[8 + j] = vs(ci_)*r + vs(cr_)*im;
        }

        // reduce-scatter over lane bits 0..3, then full adds over bits 4,5
        rstep_pk<0, 8>(W, lane);
        rstep_pk<1, 4>(W, lane);
        rstep_pk<2, 2>(W, lane);
        rstep_pk<3, 1>(W, lane);
        f2v tot = W[0];
        tot.x += __shfl_xor(tot.x, 16, 64); tot.y += __shfl_xor(tot.y, 16, 64);
        tot.x += __shfl_xor(tot.x, 32, 64); tot.y += __shfl_xor(tot.y, 32, 64);
        if (lane < 16) s_redP[wv][vidx] = tot;

        __syncthreads();
        if (tid < 16) {
            f2v r = s_redP[0][tid] + s_redP[1][tid] + s_redP[2][tid] + s_redP[3][tid];
            s_wP[tid] = r;
            s_accP[tid] += vs(poly[k]) * r;
        }
        __syncthreads();
    }

    // ---- finalize on wave 0, lane-per-amplitude (verified round 2; planar view) ----
    if (tid < 16) {
        const int l = tid;
        const float* accf = (const float*)s_accP;   // [0..15]=re, [16..31]=im
        float l1 = fabsf(poly[0]) + fabsf(poly[1]) + fabsf(poly[2]) + fabsf(poly[3]);
        float inv = 1.f / l1;
        float ar = accf[l] * inv, ai = accf[16 + l] * inv;
        float n2 = ar * ar + ai * ai;
        #pragma unroll
        for (int o = 1; o < 16; o <<= 1) n2 += __shfl_xor(n2, o, 64);
        float sc = 1.f / (sqrtf(n2) + 1e-9f);
        ar *= sc; ai *= sc;

        float s, c, pr, pi, se, ce, t0;
        #pragma unroll
        for (int w = 0; w < 4; ++w) {
            const int BIT = 8 >> w;
            fsc(0.5f * qff[3 * w + 0], s, c);            // RX
            pr = __shfl_xor(ar, BIT, 64); pi = __shfl_xor(ai, BIT, 64);
            t0 = c * ar + s * pi; ai = c * ai - s * pr; ar = t0;
            fsc(0.5f * qff[3 * w + 1], s, c);            // RY
            pr = __shfl_xor(ar, BIT, 64); pi = __shfl_xor(ai, BIT, 64);
            se = (l & BIT) ? s : -s;
            t0 = c * ar + se * pr; ai = c * ai + se * pi; ar = t0;
            fsc(0.5f * qff[3 * w + 2], s, c);            // RZ
            se = (l & BIT) ? s : -s;
            t0 = c * ar - se * ai; ai = c * ai + se * ar; ar = t0;
        }
        #define CRXF(CB, TB, hp) { fsc(0.5f * (hp), s, c);                        \
            pr = __shfl_xor(ar, TB, 64); pi = __shfl_xor(ai, TB, 64);             \
            ce = (l & CB) ? c : 1.f; se = (l & CB) ? s : 0.f;                     \
            t0 = ce * ar + se * pi; ai = ce * ai - se * pr; ar = t0; }
        CRXF(8, 4, qff[12]) CRXF(4, 2, qff[13]) CRXF(2, 1, qff[14]) CRXF(1, 8, qff[15])
        CRXF(1, 2, qff[16]) CRXF(2, 4, qff[17]) CRXF(4, 8, qff[18]) CRXF(8, 1, qff[19])
        #undef CRXF

        float* o = out + (size_t)b * 12;
        #pragma unroll
        for (int w = 0; w < 4; ++w) {
            const int BIT = 8 >> w;
            pr = __shfl_xor(ar, BIT, 64); pi = __shfl_xor(ai, BIT, 64);
            float m = (l & BIT) ? 0.f : 1.f;
            float X = m * 2.f * (ar * pr + ai * pi);
            float Y = m * 2.f * (ar * pi - ai * pr);
            float Z = m * (ar * ar + ai * ai - pr * pr - pi * pi);
            #pragma unroll
            for (int of = 1; of < 16; of <<= 1) {
                X += __shfl_xor(X, of, 64);
                Y += __shfl_xor(Y, of, 64);
                Z += __shfl_xor(Z, of, 64);
            }
            if (l == 0) { o[w] = X; o[4 + w] = Y; o[8 + w] = Z; }
        }
    }
}

extern "C" void kernel_launch(void* const* d_in, const int* in_sizes, int n_in,
                              void* d_out, int out_size, void* d_ws, size_t ws_size,
                              hipStream_t stream) {
    const float* tp   = (const float*)d_in[0];
    const float* poly = (const float*)d_in[1];
    const float* mixr = (const float*)d_in[2];
    const float* mixi = (const float*)d_in[3];
    const float* qff  = (const float*)d_in[4];
    float* out = (float*)d_out;
    const int B = in_sizes[0] / (TSTEPS * NROTS);   // 2048
    qac_kernel<<<dim3(B), dim3(BLK), 0, stream>>>(tp, poly, mixr, mixi, qff, out);
}